// Round 2
// baseline (696.121 us; speedup 1.0000x reference)
//
#include <hip/hip_runtime.h>

typedef unsigned short u16;
typedef __attribute__((ext_vector_type(8))) short short8;
typedef __attribute__((ext_vector_type(4))) float floatx4;

typedef __attribute__((address_space(1))) const void* gas_cvp;
typedef __attribute__((address_space(3))) void* las_vp;

#define DEV __device__ __forceinline__

DEV float bf2f(u16 u) { union { unsigned i; float f; } c; c.i = ((unsigned)u) << 16; return c.f; }
DEV u16 f2bf(float f) {
  union { unsigned i; float f; } c; c.f = f;
  unsigned r = c.i + 0x7FFFu + ((c.i >> 16) & 1u);
  return (u16)(r >> 16);
}
DEV u16 f2bf_trunc(float f) {
  union { unsigned i; float f; } c; c.f = f;
  return (u16)(c.i >> 16);
}
DEV unsigned pack2(float a, float b) {
  return (unsigned)f2bf_trunc(a) | ((unsigned)f2bf_trunc(b) << 16);
}
DEV void gload_lds16(const void* g, void* l) {
  __builtin_amdgcn_global_load_lds((gas_cvp)g, (las_vp)l, 16, 0, 0);
}

// ---------------------------------------------------------------------------
// f32 -> bf16 convert (4 elems/thread).  n4 = n/4.
// ---------------------------------------------------------------------------
__global__ __launch_bounds__(256)
void cvt_f32_bf16(const float* __restrict__ in, u16* __restrict__ out, int n4)
{
  const int i = blockIdx.x * 256 + threadIdx.x;
  if (i >= n4) return;
  const float4 v = ((const float4*)in)[i];
  uint2 pk;
  pk.x = (unsigned)f2bf(v.x) | ((unsigned)f2bf(v.y) << 16);
  pk.y = (unsigned)f2bf(v.z) | ((unsigned)f2bf(v.w) << 16);
  ((uint2*)out)[i] = pk;
}

// ---------------------------------------------------------------------------
// f32 transpose + bf16 downcast: in (R,C) f32 -> out (C,R) bf16.
// block (32,8), grid (C/32, R/32)
// ---------------------------------------------------------------------------
__global__ __launch_bounds__(256)
void transpose_f32_bf16(const float* __restrict__ in, u16* __restrict__ out, int R, int C)
{
  __shared__ float sh[32][33];
  const int tx = threadIdx.x, ty = threadIdx.y;
  const int r0 = blockIdx.y * 32, c0 = blockIdx.x * 32;
#pragma unroll
  for (int i = 0; i < 4; ++i)
    sh[ty + 8 * i][tx] = in[(size_t)(r0 + ty + 8 * i) * C + c0 + tx];
  __syncthreads();
#pragma unroll
  for (int i = 0; i < 4; ++i)
    out[(size_t)(c0 + ty + 8 * i) * R + r0 + tx] = f2bf(sh[tx][ty + 8 * i]);
}

// ---------------------------------------------------------------------------
// Legacy 128x(32*JN) GEMM (kept for OPROJ only, EPI 1).
// ---------------------------------------------------------------------------
template <int EPI, int JN, int BK>
__global__ __launch_bounds__(256)
void gemm_bt(const u16* __restrict__ A, const u16* __restrict__ Bt,
             int M, int N, int K,
             u16* __restrict__ out0, u16* __restrict__ out1, u16* __restrict__ out2,
             float* __restrict__ outf,
             const float* __restrict__ bias0, const float* __restrict__ bias1,
             const float* __restrict__ bias2,
             const u16* __restrict__ res_bf, const float* __restrict__ res_f,
             float* __restrict__ outf2)
{
  constexpr int BN = 32 * JN;
  constexpr int CPR = BK / 8;
  constexpr int AL = 128 * CPR / 256;
  constexpr int BL = BN * CPR / 256;
  __shared__ __align__(16) u16 As[128 * BK];
  __shared__ __align__(16) u16 Bs[BN * BK];
  const int tid = threadIdx.x;
  const int lane = tid & 63, wid = tid >> 6;
  const int wm = wid >> 1, wn = wid & 1;
  const int g = lane >> 4, c = lane & 15;
  const int m0 = blockIdx.y * 128, n0 = blockIdx.x * BN;

  int kbeg = 0, kend = K;
  if (EPI == 4) { const int Kh = K >> 1; kbeg = blockIdx.z * Kh; kend = kbeg + Kh; }

  floatx4 acc[4][JN] = {};

#pragma unroll 1
  for (int k0 = kbeg; k0 < kend; k0 += BK) {
#pragma unroll
    for (int t = 0; t < AL; ++t) {
      const int s = t * 256 + tid;
      const int row = s / CPR, q = s % CPR;
      const int qg = q ^ (row & (CPR - 1));
      gload_lds16(A + (size_t)(m0 + row) * K + k0 + qg * 8, &As[s * 8]);
    }
#pragma unroll
    for (int t = 0; t < BL; ++t) {
      const int s = t * 256 + tid;
      const int row = s / CPR, q = s % CPR;
      const int qg = q ^ (row & (CPR - 1));
      gload_lds16(Bt + (size_t)(n0 + row) * K + k0 + qg * 8, &Bs[s * 8]);
    }
    __syncthreads();
#pragma unroll
    for (int ks = 0; ks < BK / 32; ++ks) {
      short8 a[4], b[JN];
#pragma unroll
      for (int i = 0; i < 4; ++i) {
        const int row = wm * 64 + i * 16 + c;
        a[i] = *(const short8*)&As[row * BK + (((ks * 4 + g) ^ (c & (CPR - 1))) * 8)];
      }
#pragma unroll
      for (int j = 0; j < JN; ++j) {
        const int row = wn * (BN / 2) + j * 16 + c;
        b[j] = *(const short8*)&Bs[row * BK + (((ks * 4 + g) ^ (c & (CPR - 1))) * 8)];
      }
#pragma unroll
      for (int i = 0; i < 4; ++i)
#pragma unroll
        for (int j = 0; j < JN; ++j)
          acc[i][j] = __builtin_amdgcn_mfma_f32_16x16x32_bf16(a[i], b[j], acc[i][j], 0, 0, 0);
    }
    __syncthreads();
  }

#pragma unroll
  for (int i = 0; i < 4; ++i) {
#pragma unroll
    for (int j = 0; j < JN; ++j) {
      const int col = n0 + wn * (BN / 2) + j * 16 + c;
#pragma unroll
      for (int r = 0; r < 4; ++r) {
        const int row = m0 + wm * 64 + i * 16 + g * 4 + r;
        float v = acc[i][j][r];
        if (EPI == 1) {
          v += bias0[col] + bf2f(res_bf[(size_t)row * 1024 + col]);
          outf[(size_t)row * N + col] = v;
        }
      }
    }
  }
  (void)out0; (void)out1; (void)out2; (void)bias1; (void)bias2; (void)res_f; (void)outf2;
}

// ---------------------------------------------------------------------------
// 256x256 8-phase pipelined GEMM (T2 swizzle + T3/T4 counted vmcnt + T5).
// C = A(Mx ldk) * Bt(Nx ldk)^T over Kblk columns starting at kbeg.
// 512 threads, 8 waves 2Mx4N, per-wave 128x64 out, BK=64 as 2 k-slices of 32.
// LDS [2 dbuf][2 kslice][256 rows][32 cols] per operand = 128 KB total.
// Phase p stages one 16KB half-tile whose LDS region's reads retired >=1
// barrier earlier; vmcnt(8) before closing barrier of odd phases makes every
// prefetch provably complete (cross-wave) before its consuming phase begins.
// EPI 0: QKV   -> out0=q(BH,S,64), out1=k(BH,S,64), out2=vT(BH,64,S) (+bias)
// EPI 2: FFN1  -> out0 = gelu(v + bias0) bf16
// EPI 4: FFN2 split-K partials: blockIdx.z selects f0..f3, raw f32
// ---------------------------------------------------------------------------
template <int EPI>
__global__ __launch_bounds__(512, 2)
void gemm256(const u16* __restrict__ A, const u16* __restrict__ Bt,
             int M, int N, int ldk, int Kblk,
             u16* __restrict__ out0, u16* __restrict__ out1, u16* __restrict__ out2,
             const float* __restrict__ bias0, const float* __restrict__ bias1,
             const float* __restrict__ bias2,
             float* __restrict__ f0, float* __restrict__ f1,
             float* __restrict__ f2, float* __restrict__ f3)
{
  __shared__ __align__(16) u16 As[2][2][256 * 32];
  __shared__ __align__(16) u16 Bs[2][2][256 * 32];
  const int tid = threadIdx.x;
  const int lane = tid & 63, wid = tid >> 6;
  const int wm = wid >> 2, wn = wid & 3;
  const int g = lane >> 4, c = lane & 15;
  const int m0 = blockIdx.y * 256, n0 = blockIdx.x * 256;
  const int kbeg = (EPI == 4) ? blockIdx.z * Kblk : 0;
  const int NT2 = Kblk >> 6;   // number of 64-wide K tiles
  const int NIT = Kblk >> 7;   // iterations (2 tiles each)

  const int slot = (g ^ (c & 3)) * 8;
  const int r0a = (wm * 128 + c) * 32 + slot;
  const int r0b = (wn * 64 + c) * 32 + slot;

  floatx4 acc[8][4] = {};

  auto stage = [&](const u16* __restrict__ X, int rowbase, int kt, int ks, u16* lds) {
#pragma unroll
    for (int t = 0; t < 2; ++t) {
      const int s = t * 512 + tid;
      const int row = s >> 2, sl = s & 3;
      gload_lds16(X + (size_t)(rowbase + row) * ldk + (kbeg + kt * 64 + ks * 32) +
                      ((sl ^ (row & 3)) * 8),
                  lds + s * 8);
    }
  };

  // prologue: tile0.ks0, tile0.ks1, tile1.ks0  (12 load instrs outstanding)
  stage(A, m0, 0, 0, &As[0][0][0]);
  stage(Bt, n0, 0, 0, &Bs[0][0][0]);
  stage(A, m0, 0, 1, &As[0][1][0]);
  stage(Bt, n0, 0, 1, &Bs[0][1][0]);
  stage(A, m0, 1, 0, &As[1][0][0]);
  stage(Bt, n0, 1, 0, &Bs[1][0][0]);
  asm volatile("s_waitcnt vmcnt(8)" ::: "memory");
  __builtin_amdgcn_s_barrier();

  short8 a[8], b[2];
  auto lda = [&](int db, int ks) {
    const int base = (db * 2 + ks) * 8192 + r0a;
#pragma unroll
    for (int i = 0; i < 8; ++i) a[i] = *(const short8*)&As[0][0][base + i * 512];
  };
  auto ldb = [&](int db, int ks, int nh) {
    const int base = (db * 2 + ks) * 8192 + r0b + nh * 1024;
#pragma unroll
    for (int j = 0; j < 2; ++j) b[j] = *(const short8*)&Bs[0][0][base + j * 512];
  };
  auto domfma = [&](int nh) {
    __builtin_amdgcn_s_setprio(1);
#pragma unroll
    for (int i = 0; i < 8; ++i)
#pragma unroll
      for (int j = 0; j < 2; ++j)
        acc[i][nh * 2 + j] =
            __builtin_amdgcn_mfma_f32_16x16x32_bf16(a[i], b[j], acc[i][nh * 2 + j], 0, 0, 0);
    __builtin_amdgcn_s_setprio(0);
    __builtin_amdgcn_sched_barrier(0);
  };

#pragma unroll 1
  for (int it = 0; it < NIT; ++it) {
    const int t2 = 2 * it;
    const int tc2 = (t2 + 2 < NT2) ? t2 + 2 : NT2 - 1;
    const int tc3 = (t2 + 3 < NT2) ? t2 + 3 : NT2 - 1;
    // p0: read buf0.ks0 nh0 | stage A(2t+1,ks1)->buf1.ks1
    lda(0, 0); ldb(0, 0, 0);
    stage(A, m0, t2 + 1, 1, &As[1][1][0]);
    __builtin_amdgcn_s_barrier();
    domfma(0);
    __builtin_amdgcn_s_barrier();
    // p1: buf0.ks0 nh1 | stage B(2t+1,ks1)->buf1.ks1 | wait
    ldb(0, 0, 1);
    stage(Bt, n0, t2 + 1, 1, &Bs[1][1][0]);
    __builtin_amdgcn_s_barrier();
    domfma(1);
    asm volatile("s_waitcnt vmcnt(8)" ::: "memory");
    __builtin_amdgcn_s_barrier();
    // p2: buf0.ks1 nh0 | stage A(2t+2,ks0)->buf0.ks0
    lda(0, 1); ldb(0, 1, 0);
    stage(A, m0, tc2, 0, &As[0][0][0]);
    __builtin_amdgcn_s_barrier();
    domfma(0);
    __builtin_amdgcn_s_barrier();
    // p3: buf0.ks1 nh1 | stage B(2t+2,ks0)->buf0.ks0 | wait
    ldb(0, 1, 1);
    stage(Bt, n0, tc2, 0, &Bs[0][0][0]);
    __builtin_amdgcn_s_barrier();
    domfma(1);
    asm volatile("s_waitcnt vmcnt(8)" ::: "memory");
    __builtin_amdgcn_s_barrier();
    // p4: buf1.ks0 nh0 | stage A(2t+2,ks1)->buf0.ks1
    lda(1, 0); ldb(1, 0, 0);
    stage(A, m0, tc2, 1, &As[0][1][0]);
    __builtin_amdgcn_s_barrier();
    domfma(0);
    __builtin_amdgcn_s_barrier();
    // p5: buf1.ks0 nh1 | stage B(2t+2,ks1)->buf0.ks1 | wait
    ldb(1, 0, 1);
    stage(Bt, n0, tc2, 1, &Bs[0][1][0]);
    __builtin_amdgcn_s_barrier();
    domfma(1);
    asm volatile("s_waitcnt vmcnt(8)" ::: "memory");
    __builtin_amdgcn_s_barrier();
    // p6: buf1.ks1 nh0 | stage A(2t+3,ks0)->buf1.ks0
    lda(1, 1); ldb(1, 1, 0);
    stage(A, m0, tc3, 0, &As[1][0][0]);
    __builtin_amdgcn_s_barrier();
    domfma(0);
    __builtin_amdgcn_s_barrier();
    // p7: buf1.ks1 nh1 | stage B(2t+3,ks0)->buf1.ks0 | wait
    ldb(1, 1, 1);
    stage(Bt, n0, tc3, 0, &Bs[1][0][0]);
    __builtin_amdgcn_s_barrier();
    domfma(1);
    asm volatile("s_waitcnt vmcnt(8)" ::: "memory");
    __builtin_amdgcn_s_barrier();
  }
  asm volatile("s_waitcnt vmcnt(0)" ::: "memory");

  // epilogue
#pragma unroll
  for (int i = 0; i < 8; ++i) {
#pragma unroll
    for (int jj = 0; jj < 4; ++jj) {
      const int col = n0 + wn * 64 + jj * 16 + c;
#pragma unroll
      for (int r = 0; r < 4; ++r) {
        const int row = m0 + wm * 128 + i * 16 + g * 4 + r;
        float v = acc[i][jj][r];
        if (EPI == 0) {
          const int seg = col >> 10, cl = col & 1023;
          const int b_ = row >> 10, s_ = row & 1023;
          const int h_ = cl >> 6, d_ = cl & 63;
          const size_t hidx = ((size_t)(b_ * 16 + h_) * 1024 + s_) * 64 + d_;
          if (seg == 0) {
            v += bias0[cl];
            out0[hidx] = f2bf(v);
          } else if (seg == 1) {
            v += bias1[cl];
            out1[hidx] = f2bf(v);
          } else {
            v += bias2[cl];
            out2[(size_t)((b_ * 16 + h_) * 64 + d_) * 1024 + s_] = f2bf(v);
          }
        } else if (EPI == 2) {
          v += bias0[col];
          const float t2_ = 1.5957691216f * (v + 0.044715f * v * v * v);
          v = v / (1.0f + __expf(-t2_));
          out0[(size_t)row * N + col] = f2bf(v);
        } else {
          float* op = (blockIdx.z == 0) ? f0 : (blockIdx.z == 1) ? f1 : (blockIdx.z == 2) ? f2 : f3;
          op[(size_t)row * N + col] = v;
        }
      }
    }
  }
  (void)M;
}

// ---------------------------------------------------------------------------
// Flash attention (unchanged from round 0): Q-tile 128, K/V tile 64 dbuf.
// ---------------------------------------------------------------------------
__global__ __launch_bounds__(256)
void attn_kernel(const u16* __restrict__ qh, const u16* __restrict__ kh,
                 const u16* __restrict__ vt, const float* __restrict__ amask,
                 const float* __restrict__ hmask, u16* __restrict__ ctx, int layer)
{
  __shared__ __align__(16) u16 Qs[128 * 64];
  __shared__ __align__(16) u16 Ks[2][64 * 64];
  __shared__ __align__(16) u16 Vs[2][64 * 64];
  __shared__ __align__(16) u16 Ps[4][2][16 * 64];
  const int tid = threadIdx.x;
  const int lane = tid & 63, wid = tid >> 6;
  const int g = lane >> 4, c = lane & 15;
  const int qt = blockIdx.x, bh = blockIdx.y;
  const int b = bh >> 4, h = bh & 15;
  const int s0 = qt * 128;
  const float l2e = 1.44269504f;
  const float qsc = 0.125f * l2e;

#pragma unroll
  for (int t = 0; t < 4; ++t) {
    const int s = t * 256 + tid;
    const int row = s >> 3, part = s & 7;
    gload_lds16(qh + ((size_t)(bh * 1024 + s0 + row)) * 64 + ((part ^ (row & 7)) * 8),
                &Qs[s * 8]);
  }
#pragma unroll
  for (int t = 0; t < 2; ++t) {
    const int s = t * 256 + tid;
    const int row = s >> 3, part = s & 7;
    gload_lds16(kh + ((size_t)(bh * 1024 + row)) * 64 + ((part ^ (row & 7)) * 8),
                &Ks[0][s * 8]);
    gload_lds16(vt + ((size_t)(bh * 64 + row)) * 1024 + ((part ^ (row & 7)) * 8),
                &Vs[0][s * 8]);
  }

  float li[2] = {0.0f, 0.0f};
  floatx4 o[2][4] = {};

#pragma unroll 1
  for (int kt = 0; kt < 16; ++kt) {
    const int cur = kt & 1;
    __syncthreads();
    if (kt < 15) {
      const int nxt = cur ^ 1;
#pragma unroll
      for (int t = 0; t < 2; ++t) {
        const int s = t * 256 + tid;
        const int row = s >> 3, part = s & 7;
        gload_lds16(kh + ((size_t)(bh * 1024 + (kt + 1) * 64 + row)) * 64 + ((part ^ (row & 7)) * 8),
                    &Ks[nxt][s * 8]);
        gload_lds16(vt + ((size_t)(bh * 64 + row)) * 1024 + (kt + 1) * 64 + ((part ^ (row & 7)) * 8),
                    &Vs[nxt][s * 8]);
      }
    }

    float4 am[4];
#pragma unroll
    for (int j = 0; j < 4; ++j) {
      am[j] = *(const float4*)(amask + b * 1024 + kt * 64 + j * 16 + g * 4);
      am[j].x *= l2e; am[j].y *= l2e; am[j].z *= l2e; am[j].w *= l2e;
    }

    floatx4 sacc[2][4] = {};
#pragma unroll
    for (int ks = 0; ks < 2; ++ks) {
      short8 aq[2], bk[4];
#pragma unroll
      for (int m = 0; m < 2; ++m)
        aq[m] = *(const short8*)&Qs[(wid * 32 + m * 16 + c) * 64 + (((ks * 4 + g) ^ (c & 7)) * 8)];
#pragma unroll
      for (int j = 0; j < 4; ++j)
        bk[j] = *(const short8*)&Ks[cur][(j * 16 + c) * 64 + (((ks * 4 + g) ^ (c & 7)) * 8)];
#pragma unroll
      for (int m = 0; m < 2; ++m)
#pragma unroll
        for (int j = 0; j < 4; ++j)
          sacc[m][j] = __builtin_amdgcn_mfma_f32_16x16x32_bf16(bk[j], aq[m], sacc[m][j], 0, 0, 0);
    }

#pragma unroll
    for (int m = 0; m < 2; ++m) {
#pragma unroll
      for (int j = 0; j < 4; ++j) {
        const float p0 = exp2f(fmaf(sacc[m][j][0], qsc, am[j].x));
        const float p1 = exp2f(fmaf(sacc[m][j][1], qsc, am[j].y));
        const float p2 = exp2f(fmaf(sacc[m][j][2], qsc, am[j].z));
        const float p3 = exp2f(fmaf(sacc[m][j][3], qsc, am[j].w));
        li[m] += (p0 + p1) + (p2 + p3);
        uint2 pk;
        pk.x = pack2(p0, p1);
        pk.y = pack2(p2, p3);
        *(uint2*)&Ps[wid][m][c * 64 + (((2 * j + (g >> 1)) ^ (c & 7)) * 8) + (g & 1) * 4] = pk;
      }
    }
    asm volatile("" ::: "memory");

#pragma unroll
    for (int ks = 0; ks < 2; ++ks) {
      short8 ap[2], bv[4];
#pragma unroll
      for (int m = 0; m < 2; ++m)
        ap[m] = *(const short8*)&Ps[wid][m][c * 64 + (((ks * 4 + g) ^ (c & 7)) * 8)];
#pragma unroll
      for (int j = 0; j < 4; ++j)
        bv[j] = *(const short8*)&Vs[cur][(j * 16 + c) * 64 + (((ks * 4 + g) ^ (c & 7)) * 8)];
#pragma unroll
      for (int m = 0; m < 2; ++m)
#pragma unroll
        for (int j = 0; j < 4; ++j)
          o[m][j] = __builtin_amdgcn_mfma_f32_16x16x32_bf16(ap[m], bv[j], o[m][j], 0, 0, 0);
    }
  }

#pragma unroll
  for (int m = 0; m < 2; ++m) {
    li[m] += __shfl_xor(li[m], 16, 64);
    li[m] += __shfl_xor(li[m], 32, 64);
  }
  const float hm = hmask[layer * 16 + h];
  float rli[2][4];
#pragma unroll
  for (int m = 0; m < 2; ++m)
#pragma unroll
    for (int r = 0; r < 4; ++r)
      rli[m][r] = hm / __shfl(li[m], g * 4 + r, 64);

#pragma unroll
  for (int m = 0; m < 2; ++m)
#pragma unroll
    for (int j = 0; j < 4; ++j)
#pragma unroll
      for (int r = 0; r < 4; ++r) {
        const int qrow = wid * 32 + m * 16 + g * 4 + r;
        const float v = o[m][j][r] * rli[m][r];
        ctx[(size_t)(b * 1024 + s0 + qrow) * 1024 + h * 64 + j * 16 + c] = f2bf(v);
      }
}

// ---------------------------------------------------------------------------
// LayerNorm over rows of 1024 f32.  One block (256 thr) per row.
// ---------------------------------------------------------------------------
template <bool WF32>
__global__ __launch_bounds__(256)
void ln_kernel(const float* __restrict__ x, const float* __restrict__ gw,
               const float* __restrict__ bw, u16* __restrict__ ob,
               float* __restrict__ of)
{
  const int row = blockIdx.x, tid = threadIdx.x;
  const int lane = tid & 63, wid = tid >> 6;
  const float4 v = ((const float4*)(x + (size_t)row * 1024))[tid];
  float s = v.x + v.y + v.z + v.w;
#pragma unroll
  for (int d = 32; d >= 1; d >>= 1) s += __shfl_xor(s, d, 64);
  __shared__ float red[8];
  if (lane == 0) red[wid] = s;
  __syncthreads();
  const float mean = (red[0] + red[1] + red[2] + red[3]) * (1.0f / 1024.0f);
  const float d0 = v.x - mean, d1 = v.y - mean, d2 = v.z - mean, d3 = v.w - mean;
  float s2 = d0 * d0 + d1 * d1 + d2 * d2 + d3 * d3;
#pragma unroll
  for (int d = 32; d >= 1; d >>= 1) s2 += __shfl_xor(s2, d, 64);
  if (lane == 0) red[4 + wid] = s2;
  __syncthreads();
  const float var = (red[4] + red[5] + red[6] + red[7]) * (1.0f / 1024.0f);
  const float rr = rsqrtf(var + 1e-12f);
  const float4 g4 = ((const float4*)gw)[tid];
  const float4 b4 = ((const float4*)bw)[tid];
  const float y0 = d0 * rr * g4.x + b4.x;
  const float y1 = d1 * rr * g4.y + b4.y;
  const float y2 = d2 * rr * g4.z + b4.z;
  const float y3 = d3 * rr * g4.w + b4.w;
  uint2 pk;
  pk.x = (unsigned)f2bf(y0) | ((unsigned)f2bf(y1) << 16);
  pk.y = (unsigned)f2bf(y2) | ((unsigned)f2bf(y3) << 16);
  ((uint2*)(ob + (size_t)row * 1024))[tid] = pk;
  if (WF32) {
    float4 o4; o4.x = y0; o4.y = y1; o4.z = y2; o4.w = y3;
    ((float4*)(of + (size_t)row * 1024))[tid] = o4;
  }
}

// ---------------------------------------------------------------------------
// Fused LN2: x = xa+xb+xc+xd (4 split-K partials) + bias + res, then LN.
// ---------------------------------------------------------------------------
template <bool WF32>
__global__ __launch_bounds__(256)
void ln2_fused(const float* __restrict__ xa, const float* __restrict__ xb,
               const float* __restrict__ xc, const float* __restrict__ xd,
               const float* __restrict__ bias, const float* __restrict__ res,
               const float* __restrict__ gw, const float* __restrict__ bw,
               u16* __restrict__ ob, float* __restrict__ of)
{
  const int row = blockIdx.x, tid = threadIdx.x;
  const int lane = tid & 63, wid = tid >> 6;
  const float4 va = ((const float4*)(xa + (size_t)row * 1024))[tid];
  const float4 vb = ((const float4*)(xb + (size_t)row * 1024))[tid];
  const float4 vc2 = ((const float4*)(xc + (size_t)row * 1024))[tid];
  const float4 vd = ((const float4*)(xd + (size_t)row * 1024))[tid];
  const float4 vr = ((const float4*)(res + (size_t)row * 1024))[tid];
  const float4 vbi = ((const float4*)bias)[tid];
  float4 v;
  v.x = (va.x + vb.x) + (vc2.x + vd.x) + vr.x + vbi.x;
  v.y = (va.y + vb.y) + (vc2.y + vd.y) + vr.y + vbi.y;
  v.z = (va.z + vb.z) + (vc2.z + vd.z) + vr.z + vbi.z;
  v.w = (va.w + vb.w) + (vc2.w + vd.w) + vr.w + vbi.w;
  float s = v.x + v.y + v.z + v.w;
#pragma unroll
  for (int d = 32; d >= 1; d >>= 1) s += __shfl_xor(s, d, 64);
  __shared__ float red[8];
  if (lane == 0) red[wid] = s;
  __syncthreads();
  const float mean = (red[0] + red[1] + red[2] + red[3]) * (1.0f / 1024.0f);
  const float d0 = v.x - mean, d1 = v.y - mean, d2 = v.z - mean, d3 = v.w - mean;
  float s2 = d0 * d0 + d1 * d1 + d2 * d2 + d3 * d3;
#pragma unroll
  for (int d = 32; d >= 1; d >>= 1) s2 += __shfl_xor(s2, d, 64);
  if (lane == 0) red[4 + wid] = s2;
  __syncthreads();
  const float var = (red[4] + red[5] + red[6] + red[7]) * (1.0f / 1024.0f);
  const float rr = rsqrtf(var + 1e-12f);
  const float4 g4 = ((const float4*)gw)[tid];
  const float4 b4 = ((const float4*)bw)[tid];
  const float y0 = d0 * rr * g4.x + b4.x;
  const float y1 = d1 * rr * g4.y + b4.y;
  const float y2 = d2 * rr * g4.z + b4.z;
  const float y3 = d3 * rr * g4.w + b4.w;
  uint2 pk;
  pk.x = (unsigned)f2bf(y0) | ((unsigned)f2bf(y1) << 16);
  pk.y = (unsigned)f2bf(y2) | ((unsigned)f2bf(y3) << 16);
  ((uint2*)(ob + (size_t)row * 1024))[tid] = pk;
  if (WF32) {
    float4 o4; o4.x = y0; o4.y = y1; o4.z = y2; o4.w = y3;
    ((float4*)(of + (size_t)row * 1024))[tid] = o4;
  }
}

// ---------------------------------------------------------------------------
extern "C" void kernel_launch(void* const* d_in, const int* in_sizes, int n_in,
                              void* d_out, int out_size, void* d_ws, size_t ws_size,
                              hipStream_t stream)
{
  const float* hs_in = (const float*)d_in[0];
  const float* amask = (const float*)d_in[1];
  const float* hmask = (const float*)d_in[2];
  const float* q_w = (const float*)d_in[3];
  const float* q_b = (const float*)d_in[4];
  const float* k_w = (const float*)d_in[5];
  const float* k_b = (const float*)d_in[6];
  const float* v_w = (const float*)d_in[7];
  const float* v_b = (const float*)d_in[8];
  const float* o_w = (const float*)d_in[9];
  const float* o_b = (const float*)d_in[10];
  const float* attn_ln_g = (const float*)d_in[11];
  const float* attn_ln_b = (const float*)d_in[12];
  const float* w1 = (const float*)d_in[13];
  const float* b1 = (const float*)d_in[14];
  const float* w2 = (const float*)d_in[15];
  const float* b2 = (const float*)d_in[16];
  const float* ffn_ln_g = (const float*)d_in[17];
  const float* ffn_ln_b = (const float*)d_in[18];

  char* ws = (char*)d_ws;
  size_t off = 0;
  auto alloc = [&](size_t bytes) { void* p = ws + off; off += bytes; return p; };

  u16* Wqkv_t = (u16*)alloc((size_t)3072 * 1024 * 2);
  u16* Wo_t   = (u16*)alloc((size_t)1024 * 1024 * 2);
  u16* W1t    = (u16*)alloc((size_t)2 * 4096 * 1024 * 2);
  u16* W2t    = (u16*)alloc((size_t)2 * 1024 * 4096 * 2);
  u16* hs0_bf = (u16*)alloc((size_t)4096 * 1024 * 2);
  u16* qbuf   = (u16*)alloc((size_t)4096 * 1024 * 2);   // (BH,S,64); x3 alias
  u16* kbuf   = (u16*)alloc((size_t)4096 * 1024 * 2);   // (BH,S,64)
  u16* vtb    = (u16*)alloc((size_t)4096 * 1024 * 2);   // (BH,64,S); x4 alias
  u16* ctxb   = (u16*)alloc((size_t)4096 * 1024 * 2);
  u16* hbuf   = (u16*)alloc((size_t)4096 * 4096 * 2);
  float* x1     = (float*)alloc((size_t)4096 * 1024 * 4);  // OPROJ out; FFN2 partial z1
  float* attn_f = (float*)alloc((size_t)4096 * 1024 * 4);
  u16* attn_bf  = (u16*)alloc((size_t)4096 * 1024 * 2);
  float* x2     = (float*)alloc((size_t)4096 * 1024 * 4);  // FFN2 partial z0
  u16* hs2_bf   = (u16*)alloc((size_t)4096 * 1024 * 2);
  if (off > ws_size) return;
  // FFN2 partials z2/z3 reuse attention buffers (dead by FFN2 time):
  float* x3 = (float*)qbuf;   // spans qbuf+kbuf = 16 MB
  float* x4 = (float*)vtb;    // spans vtb+ctxb = 16 MB

  const dim3 tb(32, 8);
  cvt_f32_bf16<<<4096, 256, 0, stream>>>(hs_in, hs0_bf, 4096 * 1024 / 4);
  transpose_f32_bf16<<<dim3(32, 32), tb, 0, stream>>>(q_w, Wqkv_t, 1024, 1024);
  transpose_f32_bf16<<<dim3(32, 32), tb, 0, stream>>>(k_w, Wqkv_t + (size_t)1024 * 1024, 1024, 1024);
  transpose_f32_bf16<<<dim3(32, 32), tb, 0, stream>>>(v_w, Wqkv_t + (size_t)2 * 1024 * 1024, 1024, 1024);
  transpose_f32_bf16<<<dim3(32, 32), tb, 0, stream>>>(o_w, Wo_t, 1024, 1024);
  for (int l = 0; l < 2; ++l) {
    transpose_f32_bf16<<<dim3(128, 32), tb, 0, stream>>>(
        w1 + (size_t)l * 1024 * 4096, W1t + (size_t)l * 4096 * 1024, 1024, 4096);
    transpose_f32_bf16<<<dim3(32, 128), tb, 0, stream>>>(
        w2 + (size_t)l * 4096 * 1024, W2t + (size_t)l * 1024 * 4096, 4096, 1024);
  }

  for (int l = 0; l < 2; ++l) {
    const u16* hsb = l ? hs2_bf : hs0_bf;
    gemm256<0><<<dim3(12, 16), 512, 0, stream>>>(
        hsb, Wqkv_t, 4096, 3072, 1024, 1024,
        qbuf, kbuf, vtb, q_b, k_b, v_b, nullptr, nullptr, nullptr, nullptr);
    attn_kernel<<<dim3(8, 64), 256, 0, stream>>>(qbuf, kbuf, vtb, amask, hmask, ctxb, l);
    gemm_bt<1, 2, 64><<<dim3(16, 32), 256, 0, stream>>>(
        ctxb, Wo_t, 4096, 1024, 1024,
        nullptr, nullptr, nullptr, x1, o_b, nullptr, nullptr, hsb, nullptr, nullptr);
    ln_kernel<true><<<4096, 256, 0, stream>>>(x1, attn_ln_g, attn_ln_b, attn_bf, attn_f);
    gemm256<2><<<dim3(16, 16), 512, 0, stream>>>(
        attn_bf, W1t + (size_t)l * 4096 * 1024, 4096, 4096, 1024, 1024,
        hbuf, nullptr, nullptr, b1 + (size_t)l * 4096, nullptr, nullptr,
        nullptr, nullptr, nullptr, nullptr);
    // FFN2 split-K x4: z -> {x2, x1, x3, x4}
    gemm256<4><<<dim3(4, 16, 4), 512, 0, stream>>>(
        hbuf, W2t + (size_t)l * 1024 * 4096, 4096, 1024, 4096, 1024,
        nullptr, nullptr, nullptr, nullptr, nullptr, nullptr,
        x2, x1, x3, x4);
    if (l == 0) {
      ln2_fused<false><<<4096, 256, 0, stream>>>(
          x2, x1, x3, x4, b2, attn_f, ffn_ln_g, ffn_ln_b, hs2_bf, nullptr);
    } else {
      ln2_fused<true><<<4096, 256, 0, stream>>>(
          x2, x1, x3, x4, b2 + 1024, attn_f, ffn_ln_g + 1024, ffn_ln_b + 1024,
          hs2_bf, (float*)d_out);
    }
  }
  (void)in_sizes; (void)n_in; (void)out_size;
}

// Round 3
// 614.923 us; speedup vs baseline: 1.1320x; 1.1320x over previous
//
#include <hip/hip_runtime.h>

typedef unsigned short u16;
typedef __attribute__((ext_vector_type(8))) short short8;
typedef __attribute__((ext_vector_type(4))) float floatx4;

typedef __attribute__((address_space(1))) const void* gas_cvp;
typedef __attribute__((address_space(3))) void* las_vp;

#define DEV __device__ __forceinline__

DEV float bf2f(u16 u) { union { unsigned i; float f; } c; c.i = ((unsigned)u) << 16; return c.f; }
DEV u16 f2bf(float f) {
  union { unsigned i; float f; } c; c.f = f;
  unsigned r = c.i + 0x7FFFu + ((c.i >> 16) & 1u);
  return (u16)(r >> 16);
}
DEV u16 f2bf_trunc(float f) {
  union { unsigned i; float f; } c; c.f = f;
  return (u16)(c.i >> 16);
}
DEV unsigned pack2(float a, float b) {
  return (unsigned)f2bf_trunc(a) | ((unsigned)f2bf_trunc(b) << 16);
}
DEV void gload_lds16(const void* g, void* l) {
  __builtin_amdgcn_global_load_lds((gas_cvp)g, (las_vp)l, 16, 0, 0);
}

// ---------------------------------------------------------------------------
// f32 -> bf16 convert (4 elems/thread).  n4 = n/4.
// ---------------------------------------------------------------------------
__global__ __launch_bounds__(256)
void cvt_f32_bf16(const float* __restrict__ in, u16* __restrict__ out, int n4)
{
  const int i = blockIdx.x * 256 + threadIdx.x;
  if (i >= n4) return;
  const float4 v = ((const float4*)in)[i];
  uint2 pk;
  pk.x = (unsigned)f2bf(v.x) | ((unsigned)f2bf(v.y) << 16);
  pk.y = (unsigned)f2bf(v.z) | ((unsigned)f2bf(v.w) << 16);
  ((uint2*)out)[i] = pk;
}

// ---------------------------------------------------------------------------
// f32 transpose + bf16 downcast: in (R,C) f32 -> out (C,R) bf16.
// block (32,8), grid (C/32, R/32)
// ---------------------------------------------------------------------------
__global__ __launch_bounds__(256)
void transpose_f32_bf16(const float* __restrict__ in, u16* __restrict__ out, int R, int C)
{
  __shared__ float sh[32][33];
  const int tx = threadIdx.x, ty = threadIdx.y;
  const int r0 = blockIdx.y * 32, c0 = blockIdx.x * 32;
#pragma unroll
  for (int i = 0; i < 4; ++i)
    sh[ty + 8 * i][tx] = in[(size_t)(r0 + ty + 8 * i) * C + c0 + tx];
  __syncthreads();
#pragma unroll
  for (int i = 0; i < 4; ++i)
    out[(size_t)(c0 + ty + 8 * i) * R + r0 + tx] = f2bf(sh[tx][ty + 8 * i]);
}

// ---------------------------------------------------------------------------
// GEMM  C = A(MxK) * Bt(NxK)^T, bf16, global_load_lds staging w/ XOR-swizzled
// 16B chunks.  Tile 128 x (32*JN), BK 64, 256 threads (4 waves 2x2).
// XCD-bijective block swizzle on (x,y).
// EPI 0: QKV  -> out0=q(BH,S,64), out1=k(BH,S,64), out2=vT(BH,64,S)
// EPI 1: OPROJ-> outf = v + bias0 + res_bf   (f32)
// EPI 2: FFN1 -> out0 = gelu(v + bias0)      (bf16)
// EPI 3: FFN2 -> outf = v + bias0 + res_f    (f32)
// EPI 4: split-K partial (z=blockIdx.z of 2): raw f32 to outf / outf2
// ---------------------------------------------------------------------------
template <int EPI, int JN, int BK>
__global__ __launch_bounds__(256)
void gemm_bt(const u16* __restrict__ A, const u16* __restrict__ Bt,
             int M, int N, int K,
             u16* __restrict__ out0, u16* __restrict__ out1, u16* __restrict__ out2,
             float* __restrict__ outf,
             const float* __restrict__ bias0, const float* __restrict__ bias1,
             const float* __restrict__ bias2,
             const u16* __restrict__ res_bf, const float* __restrict__ res_f,
             float* __restrict__ outf2)
{
  constexpr int BN = 32 * JN;
  constexpr int CPR = BK / 8;
  constexpr int AL = 128 * CPR / 256;
  constexpr int BL = BN * CPR / 256;
  __shared__ __align__(16) u16 As[128 * BK];
  __shared__ __align__(16) u16 Bs[BN * BK];
  const int tid = threadIdx.x;
  const int lane = tid & 63, wid = tid >> 6;
  const int wm = wid >> 1, wn = wid & 1;
  const int g = lane >> 4, c = lane & 15;
  // XCD-bijective swizzle (nwg % 8 == 0 for all our grids)
  const int gx = gridDim.x, nwg = gx * gridDim.y;
  int id = blockIdx.y * gx + blockIdx.x;
  id = (id & 7) * (nwg >> 3) + (id >> 3);
  const int m0 = (id / gx) * 128, n0 = (id % gx) * BN;

  int kbeg = 0, kend = K;
  if (EPI == 4) { const int Kh = K >> 1; kbeg = blockIdx.z * Kh; kend = kbeg + Kh; }

  floatx4 acc[4][JN] = {};

#pragma unroll 1
  for (int k0 = kbeg; k0 < kend; k0 += BK) {
#pragma unroll
    for (int t = 0; t < AL; ++t) {
      const int s = t * 256 + tid;
      const int row = s / CPR, q = s % CPR;
      const int qg = q ^ (row & (CPR - 1));
      gload_lds16(A + (size_t)(m0 + row) * K + k0 + qg * 8, &As[s * 8]);
    }
#pragma unroll
    for (int t = 0; t < BL; ++t) {
      const int s = t * 256 + tid;
      const int row = s / CPR, q = s % CPR;
      const int qg = q ^ (row & (CPR - 1));
      gload_lds16(Bt + (size_t)(n0 + row) * K + k0 + qg * 8, &Bs[s * 8]);
    }
    __syncthreads();
#pragma unroll
    for (int ks = 0; ks < BK / 32; ++ks) {
      short8 a[4], b[JN];
#pragma unroll
      for (int i = 0; i < 4; ++i) {
        const int row = wm * 64 + i * 16 + c;
        a[i] = *(const short8*)&As[row * BK + (((ks * 4 + g) ^ (c & (CPR - 1))) * 8)];
      }
#pragma unroll
      for (int j = 0; j < JN; ++j) {
        const int row = wn * (BN / 2) + j * 16 + c;
        b[j] = *(const short8*)&Bs[row * BK + (((ks * 4 + g) ^ (c & (CPR - 1))) * 8)];
      }
#pragma unroll
      for (int i = 0; i < 4; ++i)
#pragma unroll
        for (int j = 0; j < JN; ++j)
          acc[i][j] = __builtin_amdgcn_mfma_f32_16x16x32_bf16(a[i], b[j], acc[i][j], 0, 0, 0);
    }
    __syncthreads();
  }

  float* opart = nullptr;
  if (EPI == 4) opart = blockIdx.z ? outf2 : outf;

#pragma unroll
  for (int i = 0; i < 4; ++i) {
#pragma unroll
    for (int j = 0; j < JN; ++j) {
      const int col = n0 + wn * (BN / 2) + j * 16 + c;
#pragma unroll
      for (int r = 0; r < 4; ++r) {
        const int row = m0 + wm * 64 + i * 16 + g * 4 + r;
        float v = acc[i][j][r];
        if (EPI == 0) {
          const int seg = col >> 10, cl = col & 1023;
          const int b_ = row >> 10, s_ = row & 1023;
          const int h_ = cl >> 6, d_ = cl & 63;
          const size_t hidx = ((size_t)(b_ * 16 + h_) * 1024 + s_) * 64 + d_;
          if (seg == 0) {
            v += bias0[cl];
            out0[hidx] = f2bf(v);
          } else if (seg == 1) {
            v += bias1[cl];
            out1[hidx] = f2bf(v);
          } else {
            v += bias2[cl];
            out2[(size_t)((b_ * 16 + h_) * 64 + d_) * 1024 + s_] = f2bf(v);
          }
        } else if (EPI == 1) {
          v += bias0[col] + bf2f(res_bf[(size_t)row * 1024 + col]);
          outf[(size_t)row * N + col] = v;
        } else if (EPI == 2) {
          v += bias0[col];
          const float t2 = 1.5957691216f * (v + 0.044715f * v * v * v);
          v = v / (1.0f + __expf(-t2));
          out0[(size_t)row * N + col] = f2bf(v);
        } else if (EPI == 3) {
          v += bias0[col] + res_f[(size_t)row * 1024 + col];
          outf[(size_t)row * N + col] = v;
        } else {
          opart[(size_t)row * N + col] = v;
        }
      }
    }
  }
}

// ---------------------------------------------------------------------------
// gemm256v2: 256x256 tile, 4-phase-per-K-tile pipelined GEMM (template port,
// attempt 2).  Fixes vs v1: no sched_barrier in loop; proven 0-conflict LDS
// layout [256][64] u16 with slot XOR (c&7); stage front-loaded (A in ph0,
// B in ph1, 4 gloads each) into the idle dbuf; single vmcnt(0) drain at ph3
// (loads have >=2 phases in flight -> wait ~free).  512 thr, 8 waves 2Mx4N,
// per-wave 128x64 out; per phase: 12 ds_read_b128 + 16 MFMA (one C-quadrant
// x K=64).  LDS 128 KB -> 1 block/CU.  FFN1 only: out = gelu(v+bias) bf16.
// ---------------------------------------------------------------------------
__global__ __launch_bounds__(512, 2)
void gemm256v2(const u16* __restrict__ A, const u16* __restrict__ Bt,
               int N, int K,
               const float* __restrict__ bias, u16* __restrict__ out)
{
  __shared__ __align__(16) u16 As[2][256 * 64];
  __shared__ __align__(16) u16 Bs[2][256 * 64];
  const int tid = threadIdx.x;
  const int lane = tid & 63, wid = tid >> 6;
  const int wm = wid >> 2, wn = wid & 3;
  const int g = lane >> 4, c = lane & 15;
  const int gx = gridDim.x, nwg = gx * gridDim.y;
  int id = blockIdx.y * gx + blockIdx.x;
  id = (id & 7) * (nwg >> 3) + (id >> 3);
  const int m0 = (id / gx) * 256, n0 = (id % gx) * 256;
  const int NT = K >> 6;

  floatx4 acc[8][4] = {};

  auto stage_half = [&](const u16* __restrict__ X, int rowbase, int t, u16* lds) {
#pragma unroll
    for (int r = 0; r < 2; ++r) {
      const int s = r * 512 + tid;
      const int sr = s >> 3, q = s & 7;
      gload_lds16(X + (size_t)(rowbase + sr) * K + t * 64 + ((q ^ (sr & 7)) * 8),
                  lds + s * 8);
    }
  };

  // prologue: stage tile 0 fully, drain, barrier
  stage_half(A, m0, 0, &As[0][0]);
  stage_half(A, m0 + 128, 0, &As[0][8192]);
  stage_half(Bt, n0, 0, &Bs[0][0]);
  stage_half(Bt, n0 + 128, 0, &Bs[0][8192]);
  asm volatile("s_waitcnt vmcnt(0)" ::: "memory");
  __builtin_amdgcn_s_barrier();

#pragma unroll 1
  for (int t = 0; t < NT; ++t) {
    const int cur = t & 1, nxt = cur ^ 1;
    const bool pre = (t + 1 < NT);
#pragma unroll
    for (int p = 0; p < 4; ++p) {
      const int ih = p >> 1, jh = p & 1;
      short8 a[4][2], b[2][2];
#pragma unroll
      for (int ks = 0; ks < 2; ++ks) {
#pragma unroll
        for (int i = 0; i < 4; ++i)
          a[i][ks] = *(const short8*)&As[cur][(wm * 128 + ih * 64 + i * 16 + c) * 64 +
                                             (((ks * 4 + g) ^ (c & 7)) * 8)];
#pragma unroll
        for (int j = 0; j < 2; ++j)
          b[j][ks] = *(const short8*)&Bs[cur][(wn * 64 + jh * 32 + j * 16 + c) * 64 +
                                             (((ks * 4 + g) ^ (c & 7)) * 8)];
      }
      if (p == 0 && pre) {
        stage_half(A, m0, t + 1, &As[nxt][0]);
        stage_half(A, m0 + 128, t + 1, &As[nxt][8192]);
      }
      if (p == 1 && pre) {
        stage_half(Bt, n0, t + 1, &Bs[nxt][0]);
        stage_half(Bt, n0 + 128, t + 1, &Bs[nxt][8192]);
      }
      __builtin_amdgcn_s_barrier();
      __builtin_amdgcn_s_setprio(1);
#pragma unroll
      for (int ks = 0; ks < 2; ++ks)
#pragma unroll
        for (int i = 0; i < 4; ++i)
#pragma unroll
          for (int j = 0; j < 2; ++j)
            acc[ih * 4 + i][jh * 2 + j] = __builtin_amdgcn_mfma_f32_16x16x32_bf16(
                a[i][ks], b[j][ks], acc[ih * 4 + i][jh * 2 + j], 0, 0, 0);
      __builtin_amdgcn_s_setprio(0);
      if (p == 3 && pre) asm volatile("s_waitcnt vmcnt(0)" ::: "memory");
      __builtin_amdgcn_s_barrier();
    }
  }

  // epilogue: gelu(v + bias) -> bf16
#pragma unroll
  for (int i = 0; i < 8; ++i)
#pragma unroll
    for (int jj = 0; jj < 4; ++jj) {
      const int col = n0 + wn * 64 + jj * 16 + c;
#pragma unroll
      for (int r = 0; r < 4; ++r) {
        const int row = m0 + wm * 128 + i * 16 + g * 4 + r;
        float v = acc[i][jj][r] + bias[col];
        const float t2_ = 1.5957691216f * (v + 0.044715f * v * v * v);
        v = v / (1.0f + __expf(-t2_));
        out[(size_t)row * N + col] = f2bf(v);
      }
    }
}

// ---------------------------------------------------------------------------
// Flash attention: Q-tile 128, K/V tile 64 dbuf.  Block swizzle groups the
// 8 same-bh blocks (sharing 256KB K/V) onto one XCD for L2 reuse.
// ---------------------------------------------------------------------------
__global__ __launch_bounds__(256)
void attn_kernel(const u16* __restrict__ qh, const u16* __restrict__ kh,
                 const u16* __restrict__ vt, const float* __restrict__ amask,
                 const float* __restrict__ hmask, u16* __restrict__ ctx, int layer)
{
  __shared__ __align__(16) u16 Qs[128 * 64];
  __shared__ __align__(16) u16 Ks[2][64 * 64];
  __shared__ __align__(16) u16 Vs[2][64 * 64];
  __shared__ __align__(16) u16 Ps[4][2][16 * 64];
  const int tid = threadIdx.x;
  const int lane = tid & 63, wid = tid >> 6;
  const int g = lane >> 4, c = lane & 15;
  // XCD swizzle: id%8 = XCD; give each XCD 8 bh values x 8 q-tiles.
  const int id = blockIdx.y * gridDim.x + blockIdx.x;
  const int x_ = id & 7, y_ = id >> 3;
  const int qt = y_ & 7;
  const int bh = x_ * 8 + (y_ >> 3);
  const int b = bh >> 4, h = bh & 15;
  const int s0 = qt * 128;
  const float l2e = 1.44269504f;
  const float qsc = 0.125f * l2e;

#pragma unroll
  for (int t = 0; t < 4; ++t) {
    const int s = t * 256 + tid;
    const int row = s >> 3, part = s & 7;
    gload_lds16(qh + ((size_t)(bh * 1024 + s0 + row)) * 64 + ((part ^ (row & 7)) * 8),
                &Qs[s * 8]);
  }
#pragma unroll
  for (int t = 0; t < 2; ++t) {
    const int s = t * 256 + tid;
    const int row = s >> 3, part = s & 7;
    gload_lds16(kh + ((size_t)(bh * 1024 + row)) * 64 + ((part ^ (row & 7)) * 8),
                &Ks[0][s * 8]);
    gload_lds16(vt + ((size_t)(bh * 64 + row)) * 1024 + ((part ^ (row & 7)) * 8),
                &Vs[0][s * 8]);
  }

  float li[2] = {0.0f, 0.0f};
  floatx4 o[2][4] = {};

#pragma unroll 1
  for (int kt = 0; kt < 16; ++kt) {
    const int cur = kt & 1;
    __syncthreads();
    if (kt < 15) {
      const int nxt = cur ^ 1;
#pragma unroll
      for (int t = 0; t < 2; ++t) {
        const int s = t * 256 + tid;
        const int row = s >> 3, part = s & 7;
        gload_lds16(kh + ((size_t)(bh * 1024 + (kt + 1) * 64 + row)) * 64 + ((part ^ (row & 7)) * 8),
                    &Ks[nxt][s * 8]);
        gload_lds16(vt + ((size_t)(bh * 64 + row)) * 1024 + (kt + 1) * 64 + ((part ^ (row & 7)) * 8),
                    &Vs[nxt][s * 8]);
      }
    }

    float4 am[4];
#pragma unroll
    for (int j = 0; j < 4; ++j) {
      am[j] = *(const float4*)(amask + b * 1024 + kt * 64 + j * 16 + g * 4);
      am[j].x *= l2e; am[j].y *= l2e; am[j].z *= l2e; am[j].w *= l2e;
    }

    floatx4 sacc[2][4] = {};
#pragma unroll
    for (int ks = 0; ks < 2; ++ks) {
      short8 aq[2], bk[4];
#pragma unroll
      for (int m = 0; m < 2; ++m)
        aq[m] = *(const short8*)&Qs[(wid * 32 + m * 16 + c) * 64 + (((ks * 4 + g) ^ (c & 7)) * 8)];
#pragma unroll
      for (int j = 0; j < 4; ++j)
        bk[j] = *(const short8*)&Ks[cur][(j * 16 + c) * 64 + (((ks * 4 + g) ^ (c & 7)) * 8)];
#pragma unroll
      for (int m = 0; m < 2; ++m)
#pragma unroll
        for (int j = 0; j < 4; ++j)
          sacc[m][j] = __builtin_amdgcn_mfma_f32_16x16x32_bf16(bk[j], aq[m], sacc[m][j], 0, 0, 0);
    }

#pragma unroll
    for (int m = 0; m < 2; ++m) {
#pragma unroll
      for (int j = 0; j < 4; ++j) {
        const float p0 = exp2f(fmaf(sacc[m][j][0], qsc, am[j].x));
        const float p1 = exp2f(fmaf(sacc[m][j][1], qsc, am[j].y));
        const float p2 = exp2f(fmaf(sacc[m][j][2], qsc, am[j].z));
        const float p3 = exp2f(fmaf(sacc[m][j][3], qsc, am[j].w));
        li[m] += (p0 + p1) + (p2 + p3);
        uint2 pk;
        pk.x = pack2(p0, p1);
        pk.y = pack2(p2, p3);
        *(uint2*)&Ps[wid][m][c * 64 + (((2 * j + (g >> 1)) ^ (c & 7)) * 8) + (g & 1) * 4] = pk;
      }
    }
    asm volatile("" ::: "memory");

#pragma unroll
    for (int ks = 0; ks < 2; ++ks) {
      short8 ap[2], bv[4];
#pragma unroll
      for (int m = 0; m < 2; ++m)
        ap[m] = *(const short8*)&Ps[wid][m][c * 64 + (((ks * 4 + g) ^ (c & 7)) * 8)];
#pragma unroll
      for (int j = 0; j < 4; ++j)
        bv[j] = *(const short8*)&Vs[cur][(j * 16 + c) * 64 + (((ks * 4 + g) ^ (c & 7)) * 8)];
#pragma unroll
      for (int m = 0; m < 2; ++m)
#pragma unroll
        for (int j = 0; j < 4; ++j)
          o[m][j] = __builtin_amdgcn_mfma_f32_16x16x32_bf16(ap[m], bv[j], o[m][j], 0, 0, 0);
    }
  }

#pragma unroll
  for (int m = 0; m < 2; ++m) {
    li[m] += __shfl_xor(li[m], 16, 64);
    li[m] += __shfl_xor(li[m], 32, 64);
  }
  const float hm = hmask[layer * 16 + h];
  float rli[2][4];
#pragma unroll
  for (int m = 0; m < 2; ++m)
#pragma unroll
    for (int r = 0; r < 4; ++r)
      rli[m][r] = hm / __shfl(li[m], g * 4 + r, 64);

#pragma unroll
  for (int m = 0; m < 2; ++m)
#pragma unroll
    for (int j = 0; j < 4; ++j)
#pragma unroll
      for (int r = 0; r < 4; ++r) {
        const int qrow = wid * 32 + m * 16 + g * 4 + r;
        const float v = o[m][j][r] * rli[m][r];
        ctx[(size_t)(b * 1024 + s0 + qrow) * 1024 + h * 64 + j * 16 + c] = f2bf(v);
      }
}

// ---------------------------------------------------------------------------
// LayerNorm over rows of 1024 f32.  One block (256 thr) per row.
// ---------------------------------------------------------------------------
template <bool WF32>
__global__ __launch_bounds__(256)
void ln_kernel(const float* __restrict__ x, const float* __restrict__ gw,
               const float* __restrict__ bw, u16* __restrict__ ob,
               float* __restrict__ of)
{
  const int row = blockIdx.x, tid = threadIdx.x;
  const int lane = tid & 63, wid = tid >> 6;
  const float4 v = ((const float4*)(x + (size_t)row * 1024))[tid];
  float s = v.x + v.y + v.z + v.w;
#pragma unroll
  for (int d = 32; d >= 1; d >>= 1) s += __shfl_xor(s, d, 64);
  __shared__ float red[8];
  if (lane == 0) red[wid] = s;
  __syncthreads();
  const float mean = (red[0] + red[1] + red[2] + red[3]) * (1.0f / 1024.0f);
  const float d0 = v.x - mean, d1 = v.y - mean, d2 = v.z - mean, d3 = v.w - mean;
  float s2 = d0 * d0 + d1 * d1 + d2 * d2 + d3 * d3;
#pragma unroll
  for (int d = 32; d >= 1; d >>= 1) s2 += __shfl_xor(s2, d, 64);
  if (lane == 0) red[4 + wid] = s2;
  __syncthreads();
  const float var = (red[4] + red[5] + red[6] + red[7]) * (1.0f / 1024.0f);
  const float rr = rsqrtf(var + 1e-12f);
  const float4 g4 = ((const float4*)gw)[tid];
  const float4 b4 = ((const float4*)bw)[tid];
  const float y0 = d0 * rr * g4.x + b4.x;
  const float y1 = d1 * rr * g4.y + b4.y;
  const float y2 = d2 * rr * g4.z + b4.z;
  const float y3 = d3 * rr * g4.w + b4.w;
  uint2 pk;
  pk.x = (unsigned)f2bf(y0) | ((unsigned)f2bf(y1) << 16);
  pk.y = (unsigned)f2bf(y2) | ((unsigned)f2bf(y3) << 16);
  ((uint2*)(ob + (size_t)row * 1024))[tid] = pk;
  if (WF32) {
    float4 o4; o4.x = y0; o4.y = y1; o4.z = y2; o4.w = y3;
    ((float4*)(of + (size_t)row * 1024))[tid] = o4;
  }
}

// ---------------------------------------------------------------------------
// Fused LN2: x = xa + xb (split-K partials) + bias + res, then LayerNorm.
// ---------------------------------------------------------------------------
template <bool WF32>
__global__ __launch_bounds__(256)
void ln2_fused(const float* __restrict__ xa, const float* __restrict__ xb,
               const float* __restrict__ bias, const float* __restrict__ res,
               const float* __restrict__ gw, const float* __restrict__ bw,
               u16* __restrict__ ob, float* __restrict__ of)
{
  const int row = blockIdx.x, tid = threadIdx.x;
  const int lane = tid & 63, wid = tid >> 6;
  const float4 va = ((const float4*)(xa + (size_t)row * 1024))[tid];
  const float4 vb = ((const float4*)(xb + (size_t)row * 1024))[tid];
  const float4 vr = ((const float4*)(res + (size_t)row * 1024))[tid];
  const float4 vc = ((const float4*)bias)[tid];
  float4 v;
  v.x = va.x + vb.x + vr.x + vc.x;
  v.y = va.y + vb.y + vr.y + vc.y;
  v.z = va.z + vb.z + vr.z + vc.z;
  v.w = va.w + vb.w + vr.w + vc.w;
  float s = v.x + v.y + v.z + v.w;
#pragma unroll
  for (int d = 32; d >= 1; d >>= 1) s += __shfl_xor(s, d, 64);
  __shared__ float red[8];
  if (lane == 0) red[wid] = s;
  __syncthreads();
  const float mean = (red[0] + red[1] + red[2] + red[3]) * (1.0f / 1024.0f);
  const float d0 = v.x - mean, d1 = v.y - mean, d2 = v.z - mean, d3 = v.w - mean;
  float s2 = d0 * d0 + d1 * d1 + d2 * d2 + d3 * d3;
#pragma unroll
  for (int d = 32; d >= 1; d >>= 1) s2 += __shfl_xor(s2, d, 64);
  if (lane == 0) red[4 + wid] = s2;
  __syncthreads();
  const float var = (red[4] + red[5] + red[6] + red[7]) * (1.0f / 1024.0f);
  const float rr = rsqrtf(var + 1e-12f);
  const float4 g4 = ((const float4*)gw)[tid];
  const float4 b4 = ((const float4*)bw)[tid];
  const float y0 = d0 * rr * g4.x + b4.x;
  const float y1 = d1 * rr * g4.y + b4.y;
  const float y2 = d2 * rr * g4.z + b4.z;
  const float y3 = d3 * rr * g4.w + b4.w;
  uint2 pk;
  pk.x = (unsigned)f2bf(y0) | ((unsigned)f2bf(y1) << 16);
  pk.y = (unsigned)f2bf(y2) | ((unsigned)f2bf(y3) << 16);
  ((uint2*)(ob + (size_t)row * 1024))[tid] = pk;
  if (WF32) {
    float4 o4; o4.x = y0; o4.y = y1; o4.z = y2; o4.w = y3;
    ((float4*)(of + (size_t)row * 1024))[tid] = o4;
  }
}

// ---------------------------------------------------------------------------
extern "C" void kernel_launch(void* const* d_in, const int* in_sizes, int n_in,
                              void* d_out, int out_size, void* d_ws, size_t ws_size,
                              hipStream_t stream)
{
  const float* hs_in = (const float*)d_in[0];
  const float* amask = (const float*)d_in[1];
  const float* hmask = (const float*)d_in[2];
  const float* q_w = (const float*)d_in[3];
  const float* q_b = (const float*)d_in[4];
  const float* k_w = (const float*)d_in[5];
  const float* k_b = (const float*)d_in[6];
  const float* v_w = (const float*)d_in[7];
  const float* v_b = (const float*)d_in[8];
  const float* o_w = (const float*)d_in[9];
  const float* o_b = (const float*)d_in[10];
  const float* attn_ln_g = (const float*)d_in[11];
  const float* attn_ln_b = (const float*)d_in[12];
  const float* w1 = (const float*)d_in[13];
  const float* b1 = (const float*)d_in[14];
  const float* w2 = (const float*)d_in[15];
  const float* b2 = (const float*)d_in[16];
  const float* ffn_ln_g = (const float*)d_in[17];
  const float* ffn_ln_b = (const float*)d_in[18];

  char* ws = (char*)d_ws;
  size_t off = 0;
  auto alloc = [&](size_t bytes) { void* p = ws + off; off += bytes; return p; };

  u16* Wqkv_t = (u16*)alloc((size_t)3072 * 1024 * 2);
  u16* Wo_t   = (u16*)alloc((size_t)1024 * 1024 * 2);
  u16* W1t    = (u16*)alloc((size_t)2 * 4096 * 1024 * 2);
  u16* W2t    = (u16*)alloc((size_t)2 * 1024 * 4096 * 2);
  u16* hs0_bf = (u16*)alloc((size_t)4096 * 1024 * 2);
  u16* qbuf   = (u16*)alloc((size_t)4096 * 1024 * 2);   // (BH,S,64)
  u16* kbuf   = (u16*)alloc((size_t)4096 * 1024 * 2);   // (BH,S,64)
  u16* vtb    = (u16*)alloc((size_t)4096 * 1024 * 2);   // (BH,64,S)
  u16* ctxb   = (u16*)alloc((size_t)4096 * 1024 * 2);
  u16* hbuf   = (u16*)alloc((size_t)4096 * 4096 * 2);
  float* x1     = (float*)alloc((size_t)4096 * 1024 * 4);  // OPROJ out; FFN2 partial z1
  float* attn_f = (float*)alloc((size_t)4096 * 1024 * 4);
  u16* attn_bf  = (u16*)alloc((size_t)4096 * 1024 * 2);
  float* x2     = (float*)alloc((size_t)4096 * 1024 * 4);  // FFN2 partial z0
  u16* hs2_bf   = (u16*)alloc((size_t)4096 * 1024 * 2);
  if (off > ws_size) return;

  const dim3 tb(32, 8);
  cvt_f32_bf16<<<4096, 256, 0, stream>>>(hs_in, hs0_bf, 4096 * 1024 / 4);
  transpose_f32_bf16<<<dim3(32, 32), tb, 0, stream>>>(q_w, Wqkv_t, 1024, 1024);
  transpose_f32_bf16<<<dim3(32, 32), tb, 0, stream>>>(k_w, Wqkv_t + (size_t)1024 * 1024, 1024, 1024);
  transpose_f32_bf16<<<dim3(32, 32), tb, 0, stream>>>(v_w, Wqkv_t + (size_t)2 * 1024 * 1024, 1024, 1024);
  transpose_f32_bf16<<<dim3(32, 32), tb, 0, stream>>>(o_w, Wo_t, 1024, 1024);
  for (int l = 0; l < 2; ++l) {
    transpose_f32_bf16<<<dim3(128, 32), tb, 0, stream>>>(
        w1 + (size_t)l * 1024 * 4096, W1t + (size_t)l * 4096 * 1024, 1024, 4096);
    transpose_f32_bf16<<<dim3(32, 128), tb, 0, stream>>>(
        w2 + (size_t)l * 4096 * 1024, W2t + (size_t)l * 1024 * 4096, 4096, 1024);
  }

  for (int l = 0; l < 2; ++l) {
    const u16* hsb = l ? hs2_bf : hs0_bf;
    gemm_bt<0, 4, 64><<<dim3(24, 32), 256, 0, stream>>>(
        hsb, Wqkv_t, 4096, 3072, 1024,
        qbuf, kbuf, vtb, nullptr, q_b, k_b, v_b, nullptr, nullptr, nullptr);
    attn_kernel<<<dim3(8, 64), 256, 0, stream>>>(qbuf, kbuf, vtb, amask, hmask, ctxb, l);
    gemm_bt<1, 2, 64><<<dim3(16, 32), 256, 0, stream>>>(
        ctxb, Wo_t, 4096, 1024, 1024,
        nullptr, nullptr, nullptr, x1, o_b, nullptr, nullptr, hsb, nullptr, nullptr);
    ln_kernel<true><<<4096, 256, 0, stream>>>(x1, attn_ln_g, attn_ln_b, attn_bf, attn_f);
    // FFN1 A/B: layer 0 -> new 256^2 pipelined kernel; layer 1 -> old path.
    if (l == 0) {
      gemm256v2<<<dim3(16, 16), 512, 0, stream>>>(
          attn_bf, W1t, 4096, 1024, b1, hbuf);
    } else {
      gemm_bt<2, 4, 64><<<dim3(32, 32), 256, 0, stream>>>(
          attn_bf, W1t + (size_t)4096 * 1024, 4096, 4096, 1024,
          hbuf, nullptr, nullptr, nullptr, b1 + 4096, nullptr, nullptr,
          nullptr, nullptr, nullptr);
    }
    // FFN2 split-K x2: z=0 -> x2, z=1 -> x1 (x1 free after LN1)
    gemm_bt<4, 4, 64><<<dim3(8, 32, 2), 256, 0, stream>>>(
        hbuf, W2t + (size_t)l * 1024 * 4096, 4096, 1024, 4096,
        nullptr, nullptr, nullptr, x2, nullptr, nullptr, nullptr,
        nullptr, nullptr, x1);
    if (l == 0) {
      ln2_fused<false><<<4096, 256, 0, stream>>>(
          x2, x1, b2, attn_f, ffn_ln_g, ffn_ln_b, hs2_bf, nullptr);
    } else {
      ln2_fused<true><<<4096, 256, 0, stream>>>(
          x2, x1, b2 + 1024, attn_f, ffn_ln_g + 1024, ffn_ln_b + 1024,
          hs2_bf, (float*)d_out);
    }
  }
  (void)in_sizes; (void)n_in; (void)out_size;
}